// Round 1
// 1001.432 us; speedup vs baseline: 1.1539x; 1.1539x over previous
//
#include <hip/hip_runtime.h>

// 3x3 stride-1 VALID conv, NCHW fp32 in/out, bf16 MFMA implicit GEMM.
// N=16, Cin=Cout=32, 512x512 -> 510x510.
// D[m=co][n=pixel], K=ci (32 = one MFMA K), 9 taps accumulate.
// Weights pre-formatted to bf16 A-fragments in d_ws by a prep kernel.
// X staged to LDS as bf16 [pixel][ci] with 72B pixel stride (conflict-free b64 ops).

namespace {
constexpr int NI    = 16;
constexpr int C_IN  = 32;
constexpr int HI    = 512;
constexpr int WI    = 512;
constexpr int C_OUT = 32;
constexpr int HO    = 510;
constexpr int WO    = 510;

constexpr int RT    = 6;        // output rows per block
constexpr int PT    = 64;       // output x-pixels per block (4 waves x 16)
constexpr int XROWS = RT + 2;   // 8 staged input rows
constexpr int XCOLS = PT + 2;   // 66 staged input cols
constexpr int PSTR  = 36;       // shorts per pixel (32 ci + 4 pad -> 72B stride, 8B aligned)
constexpr int HIWI  = HI * WI;
}

typedef __attribute__((ext_vector_type(4))) float  floatx4;
typedef __attribute__((ext_vector_type(8))) __bf16 bf16x8;
typedef __attribute__((ext_vector_type(4))) __bf16 bf16x4;
typedef __attribute__((ext_vector_type(4))) unsigned short ushortx4;

// ---- weight prep: w [co][ci][3][3] f32 -> ws bf16 A-fragments [tap][h][lane][j]
// lane = quad*16 + l16; element j: co = h*16 + l16, ci = quad*8 + j.
__global__ void conv_wprep(const float* __restrict__ w, __bf16* __restrict__ ws) {
  const int t = threadIdx.x;
  for (int i = t; i < 9 * 2 * 64 * 8; i += 256) {
    const int j    = i & 7;
    const int lane = (i >> 3) & 63;
    const int h    = (i >> 9) & 1;
    const int tap  = i >> 10;
    const int co   = h * 16 + (lane & 15);
    const int ci   = (lane >> 4) * 8 + j;
    ws[i] = (__bf16)w[(co * C_IN + ci) * 9 + tap];
  }
}

__global__ __launch_bounds__(256, 4)
void conv3x3_mfma(const float* __restrict__ x, const __bf16* __restrict__ ws,
                  const float* __restrict__ bias, float* __restrict__ out) {
  __shared__ unsigned short lds[XROWS * XCOLS * PSTR];  // 38016 B -> 4 blocks/CU

  const int t    = threadIdx.x;
  const int lane = t & 63;
  const int wv   = t >> 6;
  const int quad = lane >> 4;
  const int l16  = lane & 15;

  const int x0 = blockIdx.x * PT;
  const int y0 = blockIdx.y * RT;
  const int n  = blockIdx.z;

  // ---- stage X tile: 528 pixels x 32 ci. One pixel per lane-iteration:
  // per ci the wave's 64 loads are 64 consecutive floats (coalesced dwords);
  // pack 32 bf16 in regs, then 8x ds_write_b64 (72B lane stride = bank-minimum).
  for (int p = t; p < XROWS * XCOLS; p += 256) {
    const int row = p / XCOLS;
    const int col = p - row * XCOLS;
    int gx = x0 + col;
    if (gx > WI - 1) gx = WI - 1;   // clamp last tile's halo (values unused by valid outputs)
    const float* xp = x + ((size_t)(n * C_IN) * HI + (y0 + row)) * WI + gx;
    union { __bf16 b[32]; ushortx4 q[8]; } pk;
#pragma unroll
    for (int ci = 0; ci < C_IN; ++ci)
      pk.b[ci] = (__bf16)xp[ci * HIWI];
    unsigned short* dst = &lds[p * PSTR];
#pragma unroll
    for (int k = 0; k < 8; ++k)
      *reinterpret_cast<ushortx4*>(dst + k * 4) = pk.q[k];
  }

  // ---- A fragments: 18 coalesced 16B loads from prepped ws (L2-resident)
  bf16x8 afrag[9][2];
#pragma unroll
  for (int tap = 0; tap < 9; ++tap)
#pragma unroll
    for (int h = 0; h < 2; ++h)
      afrag[tap][h] = *reinterpret_cast<const bf16x8*>(ws + ((tap * 2 + h) * 64 + lane) * 8);

  // bias per accumulator register: D row (m=co) = quad*4 + r (+16 for second half)
  float b0[4], b1[4];
#pragma unroll
  for (int r = 0; r < 4; ++r) {
    b0[r] = bias[quad * 4 + r];
    b1[r] = bias[quad * 4 + r + 16];
  }

  __syncthreads();

  const int pbase  = wv * 16 + l16;   // B-fragment column n = l16
  const int px     = x0 + pbase;
  const bool valid = px < WO;

  for (int row = 0; row < RT; ++row) {
    floatx4 acc0 = {b0[0], b0[1], b0[2], b0[3]};
    floatx4 acc1 = {b1[0], b1[1], b1[2], b1[3]};
#pragma unroll
    for (int ky = 0; ky < 3; ++ky)
#pragma unroll
      for (int kx = 0; kx < 3; ++kx) {
        // B: lane holds X[ci = quad*8 + j][pixel = pbase + kx] at row row+ky.
        // 72B stride is 8B-aligned only -> read as two b64 halves (bank-minimum).
        union { bf16x8 v; bf16x4 h[2]; } bf;
        const int base = ((row + ky) * XCOLS + pbase + kx) * PSTR + quad * 8;
        bf.h[0] = *reinterpret_cast<const bf16x4*>(&lds[base]);
        bf.h[1] = *reinterpret_cast<const bf16x4*>(&lds[base + 4]);
        acc0 = __builtin_amdgcn_mfma_f32_16x16x32_bf16(afrag[ky * 3 + kx][0], bf.v, acc0, 0, 0, 0);
        acc1 = __builtin_amdgcn_mfma_f32_16x16x32_bf16(afrag[ky * 3 + kx][1], bf.v, acc1, 0, 0, 0);
      }
    if (valid) {
      float* op = out + ((size_t)(n * C_OUT + quad * 4) * HO + (y0 + row)) * WO + px;
#pragma unroll
      for (int r = 0; r < 4; ++r) {
        op[r * (HO * WO)]        = acc0[r];   // co = quad*4 + r
        op[(16 + r) * (HO * WO)] = acc1[r];   // co = 16 + quad*4 + r
      }
    }
  }
}

extern "C" void kernel_launch(void* const* d_in, const int* in_sizes, int n_in,
                              void* d_out, int out_size, void* d_ws, size_t ws_size,
                              hipStream_t stream) {
  const float* x    = (const float*)d_in[0];
  const float* w    = (const float*)d_in[1];
  const float* bias = (const float*)d_in[2];
  float* out        = (float*)d_out;
  __bf16* ws        = (__bf16*)d_ws;          // needs 18432 B

  conv_wprep<<<dim3(1), 256, 0, stream>>>(w, ws);

  dim3 grid(WI / PT, HO / RT, NI);  // 8 x 85 x 16 = 10880 blocks, 256 threads
  conv3x3_mfma<<<grid, 256, 0, stream>>>(x, ws, bias, out);
}